// Round 5
// baseline (125.377 us; speedup 1.0000x reference)
//
#include <hip/hip_runtime.h>

// RBFNN fused, round 5: fp8 GEMM1 + 32-row blocks -> 58KB LDS -> 2 blocks/CU.
// out[B,K] = exp(-gamma * dist(x, centers)) @ W^T + b
// B=16384, F=512, C=1024, K=100.
//
// R4 evidence: waves in ONE block all stall on the same barrier vmcnt(0)
// drain (8 waves gave +8% only); overlap needs 2 independent blocks/CU.
// LDS cut to ~58KB via fp8 G1 (x,centers e4m3; norms fp32 -> error ~1e-3
// relative on phi~1e-10, vs 6.2e-4 output threshold: free) and 32-row
// tiles; 512 blocks x 256 thr -> 2 blocks/CU. One ds_read_b128 now covers
// k=64 per frag (fp8 packs both MFMA sub-steps), halving G1 LDS traffic.
// Prepass writes centers/W into d_ws in the exact permuted+XOR-swizzled
// layout that a contiguous global_load_lds deposits bank-optimally:
//   cb: 16B cell (col, cell)=lg^(col&3) holds k-slices (s=0|1, lg) paired;
//   wb: bf16, cell (kout, cell)=(4s+lg)^(kout&7).
// GEMM2 stays bf16 (phi ~1e-10 underflows fp8). Pipeline skeleton = R2/R4:
// 2x16KB bufs, issue-at-top, barrier per stage; E0 W0 W1 E1 W2 W3.

#define NB 16384
#define NF 512
#define NC 1024
#define NK 100

#define A_PITCH 528   // bytes/row (512 fp8 + 16 pad); 132 words % 32 == 4
#define P_PITCH 272   // bytes/row (128 bf16 + 8 pad);  68 words % 32 == 4

#define CB_BYTES (NC * NF)              // 512KB fp8 centers (permuted)
#define WB_BYTES (16 * 16384)           // 16 slabs x 16KB bf16 W (permuted)
#define WS_NEED (CB_BYTES + NC * 4 + WB_BYTES)

typedef __attribute__((ext_vector_type(8))) short short8;
typedef __attribute__((ext_vector_type(4))) short short4v;
typedef __attribute__((ext_vector_type(4))) float f4;
typedef __attribute__((ext_vector_type(4))) unsigned int uint4v;
typedef __attribute__((ext_vector_type(2))) unsigned long ulong2v;
typedef unsigned short ushort;
typedef unsigned int uint;

__device__ __forceinline__ short bf16t(float f) {
  return (short)(__float_as_uint(f) >> 16);
}

__device__ __forceinline__ uint pk4_fp8(float a, float b, float c, float d) {
  uint r = __builtin_amdgcn_cvt_pk_fp8_f32(a, b, 0, false);
  return __builtin_amdgcn_cvt_pk_fp8_f32(c, d, r, true);
}

__device__ __forceinline__ void async_cp16(const void* g, void* l) {
  __builtin_amdgcn_global_load_lds(
      (const __attribute__((address_space(1))) void*)g,
      (__attribute__((address_space(3))) void*)l, 16, 0, 0);
}

// ---------------- prepass kernels ----------------

// centers [1024,512] fp32 -> cb fp8 permuted slabs + csq fp32.
// slab (c,kb): 256 cols x 64 k; 16B cell at (col, cell=lg^(col&3)) holds
// bytes fp8(centers[c*256+col][kb*64 + s*32 + lg*8 + j]), s in {0,1}.
__global__ __launch_bounds__(256) void prep_centers(
    const float* __restrict__ ctr, char* __restrict__ cb,
    float* __restrict__ csq) {
  const int t = blockIdx.x * 256 + threadIdx.x;  // 0..8191
  const int cg = t >> 3;                          // center row 0..1023
  const int kb = t & 7;
  const f4* src = (const f4*)(ctr + (size_t)cg * NF + kb * 64);
  float f[64];
  float ss = 0.f;
#pragma unroll
  for (int i = 0; i < 16; ++i) {
    f4 v = src[i];
    f[4 * i] = v.x; f[4 * i + 1] = v.y; f[4 * i + 2] = v.z; f[4 * i + 3] = v.w;
    ss += v.x * v.x + v.y * v.y + v.z * v.z + v.w * v.w;
  }
  uint w[16];
#pragma unroll
  for (int m = 0; m < 16; ++m)
    w[m] = pk4_fp8(f[4 * m], f[4 * m + 1], f[4 * m + 2], f[4 * m + 3]);
  const int c = cg >> 8, col = cg & 255;
  char* base = cb + (size_t)((c * 8 + kb) * 256 + col) * 64;
#pragma unroll
  for (int lg = 0; lg < 4; ++lg) {
    uint4v u = {w[2 * lg], w[2 * lg + 1], w[8 + 2 * lg], w[9 + 2 * lg]};
    *(uint4v*)(base + ((lg ^ (col & 3)) << 4)) = u;
  }
  // csq: sum over the 8 kb-threads (lane groups of 8)
  ss += __shfl_down(ss, 4, 64);
  ss += __shfl_down(ss, 2, 64);
  ss += __shfl_down(ss, 1, 64);
  if (kb == 0) csq[cg] = ss;
}

// W [100,1024] fp32 -> wb bf16 permuted slabs (kouts padded to 128, zeros).
// slab (c,u): 128 kouts x 64 c-cols; 16B cell at (kout, cell=(4s+lg)^(kout&7))
// holds bf16 W[kout][c*256 + u*64 + s*32 + lg*8 + (0..7)].
__global__ __launch_bounds__(256) void prep_w(const float* __restrict__ W,
                                              char* __restrict__ wb) {
  const int t = blockIdx.x * 256 + threadIdx.x;  // 0..2047
  const int kout = t >> 4;
  const int c = (t >> 2) & 3, u = t & 3;
  char* base = wb + (size_t)((c * 4 + u) * 128 + kout) * 128;
#pragma unroll
  for (int sl = 0; sl < 8; ++sl) {
    const int s = sl >> 2, lg = sl & 3;
    short4v h0 = {0, 0, 0, 0}, h1 = {0, 0, 0, 0};
    if (kout < NK) {
      const float* src = W + (size_t)kout * NC + c * 256 + u * 64 + s * 32 + lg * 8;
      f4 v0 = ((const f4*)src)[0], v1 = ((const f4*)src)[1];
      h0.x = bf16t(v0.x); h0.y = bf16t(v0.y); h0.z = bf16t(v0.z); h0.w = bf16t(v0.w);
      h1.x = bf16t(v1.x); h1.y = bf16t(v1.y); h1.z = bf16t(v1.z); h1.w = bf16t(v1.w);
    }
    char* dst = base + ((sl ^ (kout & 7)) << 4);
    *(short4v*)dst = h0;
    *(short4v*)(dst + 8) = h1;
  }
}

// ---------------- main kernel ----------------

__global__ __launch_bounds__(256, 2)
void rbf_main(const float* __restrict__ x, const char* __restrict__ cbp,
              const float* __restrict__ csqp, const char* __restrict__ wbp,
              const float* __restrict__ bvec, const float* __restrict__ gamma_p,
              float* __restrict__ out) {
  __shared__ alignas(16) char a_lds[32 * A_PITCH];    // 16896 B, x fp8 (permuted)
  __shared__ alignas(16) char bufs[2][16384];         // 32768 B, B/W dbuf
  __shared__ alignas(16) char phi_lds[32 * P_PITCH];  // 8704 B, phi bf16 half
  __shared__ float xsq[32];

  const int tid = threadIdx.x;
  const int lane = tid & 63;
  const int wv = tid >> 6;   // 0..3: G1 col group / G2 kout group
  const int lm = lane & 15;
  const int lg = lane >> 4;
  const int m0 = blockIdx.x * 32;
  const float gma = gamma_p[0];

  // slab staging: contiguous 16KB; lane L of wave wv lands at LDS
  // (wv*1024 + ir*4096 + L*16) reading the same global offset (prepass-baked).
  auto issue = [&](const char* gbase, int pb) {
    char* l = bufs[pb] + (wv << 10);
#pragma unroll
    for (int ir = 0; ir < 4; ++ir)
      async_cp16(gbase + ((ir * 256 + tid) << 4), l + ir * 4096);
  };

  // ---- prologue: issue B slab 0, stage x tile (fp32->fp8 permuted) ----
  issue(cbp, 0);
  {
    const int row = tid >> 3;   // 0..31
    const int seg = tid & 7;    // kb block 0..7 (64 k each)
    const f4* xr = (const f4*)(x + (size_t)(m0 + row) * NF + seg * 64);
    float f[64];
    float ss = 0.f;
#pragma unroll
    for (int i = 0; i < 16; ++i) {
      f4 v = xr[i];
      f[4 * i] = v.x; f[4 * i + 1] = v.y; f[4 * i + 2] = v.z; f[4 * i + 3] = v.w;
      ss += v.x * v.x + v.y * v.y + v.z * v.z + v.w * v.w;
    }
    uint w[16];
#pragma unroll
    for (int m = 0; m < 16; ++m)
      w[m] = pk4_fp8(f[4 * m], f[4 * m + 1], f[4 * m + 2], f[4 * m + 3]);
    char* ar = a_lds + row * A_PITCH + seg * 64;
#pragma unroll
    for (int l2 = 0; l2 < 4; ++l2) {
      uint4v u = {w[2 * l2], w[2 * l2 + 1], w[8 + 2 * l2], w[9 + 2 * l2]};
      *(uint4v*)(ar + l2 * 16) = u;
    }
    ((float*)phi_lds)[tid] = ss;  // scratch partials [row*8+seg]
  }
  __syncthreads();  // drains B0 + x tile
  if (tid < 32) {
    const float* pp = (const float*)phi_lds + 8 * tid;
    xsq[tid] = pp[0] + pp[1] + pp[2] + pp[3] + pp[4] + pp[5] + pp[6] + pp[7];
  }  // first read at E0, many barriers later

  const f4 fzero = {0.f, 0.f, 0.f, 0.f};
  f4 acc2[2][2];
#pragma unroll
  for (int i = 0; i < 2; ++i)
#pragma unroll
    for (int n = 0; n < 2; ++n) acc2[i][n] = fzero;

  f4 acc1[2][4];

  // GEMM1: wave tile 32 rows x 64 cols (col frags wv+4t); fp8 k=64/stage.
  auto compute1 = [&](const char* buf, int kb) {
    ulong2v a2[2], b2[4];
#pragma unroll
    for (int i = 0; i < 2; ++i)
      a2[i] = *(const ulong2v*)(a_lds + (16 * i + lm) * A_PITCH + kb * 64 +
                                lg * 16);
#pragma unroll
    for (int t = 0; t < 4; ++t)
      b2[t] = *(const ulong2v*)(buf + ((16 * (wv + 4 * t) + lm) << 6) +
                                ((lg ^ (lm & 3)) << 4));
#pragma unroll
    for (int i = 0; i < 2; ++i)
#pragma unroll
      for (int t = 0; t < 4; ++t)
        acc1[i][t] = __builtin_amdgcn_mfma_f32_16x16x32_fp8_fp8(
            (long)a2[i].x, (long)b2[t].x, acc1[i][t], 0, 0, 0);
#pragma unroll
    for (int i = 0; i < 2; ++i)
#pragma unroll
      for (int t = 0; t < 4; ++t)
        acc1[i][t] = __builtin_amdgcn_mfma_f32_16x16x32_fp8_fp8(
            (long)a2[i].y, (long)b2[t].y, acc1[i][t], 0, 0, 0);
  };

  // GEMM2: bf16; wave owns 32 kouts (frags 2wv, 2wv+1); u = 64 c-cols.
  auto compute2 = [&](const char* buf, int u) {
    const int ub = (u & 1) * 128;
#pragma unroll
    for (int s = 0; s < 2; ++s) {
      short8 pv[2], wf[2];
#pragma unroll
      for (int i = 0; i < 2; ++i)
        pv[i] = *(const short8*)(phi_lds + (16 * i + lm) * P_PITCH + ub +
                                 s * 64 + lg * 16);
#pragma unroll
      for (int n = 0; n < 2; ++n)
        wf[n] = *(const short8*)(buf + ((16 * (2 * wv + n) + lm) << 7) +
                                 (((4 * s + lg) ^ (lm & 7)) << 4));
#pragma unroll
      for (int i = 0; i < 2; ++i)
#pragma unroll
        for (int n = 0; n < 2; ++n)
          acc2[i][n] = __builtin_amdgcn_mfma_f32_16x16x32_bf16(
              pv[i], wf[n], acc2[i][n], 0, 0, 0);
    }
  };

  int p = 0;
  for (int c = 0; c < 4; ++c) {
    const char* cb_c = cbp + (size_t)c * 8 * 16384;
    const char* wb_c = wbp + (size_t)c * 4 * 16384;
    float csr[4];
#pragma unroll
    for (int t = 0; t < 4; ++t)
      csr[t] = csqp[c * 256 + 16 * (wv + 4 * t) + lm];

#pragma unroll
    for (int i = 0; i < 2; ++i)
#pragma unroll
      for (int t = 0; t < 4; ++t) acc1[i][t] = fzero;

    auto epilogue_half = [&](int hh) {
#pragma unroll
      for (int t2 = 0; t2 < 2; ++t2) {
        const int t = 2 * hh + t2;
        const float cs = csr[t];
        const int colh = 16 * (wv + 4 * t2) + lm;
#pragma unroll
        for (int i = 0; i < 2; ++i) {
#pragma unroll
          for (int r = 0; r < 4; ++r) {
            const int rowL = 16 * i + 4 * lg + r;
            float d2 = xsq[rowL] + cs - 2.0f * acc1[i][t][r];
            d2 = fmaxf(d2, 0.f);
            const float ph = __expf(-gma * __builtin_amdgcn_sqrtf(d2));
            *(short*)(phi_lds + rowL * P_PITCH + colh * 2) = bf16t(ph);
          }
        }
      }
    };

    // ---- GEMM1: 8 k=64 stages, issue next at top, barrier per stage ----
#pragma unroll
    for (int kb = 0; kb < 8; ++kb) {
      if (kb < 7) issue(cb_c + (size_t)(kb + 1) * 16384, p ^ 1);
      else        issue(wb_c, p ^ 1);
      compute1(bufs[p], kb);
      __syncthreads();
      p ^= 1;
    }

    // ---- E0 | W0 | W1 | E1 | W2 | W3 ----
    issue(wb_c + 16384, p ^ 1);
    epilogue_half(0);
    __syncthreads();          // publishes phi half-0; no flip

    compute2(bufs[p], 0);
    __syncthreads();
    p ^= 1;

    issue(wb_c + 2 * 16384, p ^ 1);
    compute2(bufs[p], 1);
    __syncthreads();          // all waves done reading phi half-0
    p ^= 1;

    issue(wb_c + 3 * 16384, p ^ 1);
    epilogue_half(1);
    __syncthreads();          // publishes phi half-1; no flip

    compute2(bufs[p], 2);
    __syncthreads();
    p ^= 1;

    if (c < 3) issue(cbp + (size_t)(c + 1) * 8 * 16384, p ^ 1);
    compute2(bufs[p], 3);
    __syncthreads();
    p ^= 1;
  }

  // ---- out = acc2 + b, kout = 16*(2wv+n)+lm < 100 ----
#pragma unroll
  for (int i = 0; i < 2; ++i) {
#pragma unroll
    for (int n = 0; n < 2; ++n) {
      const int kout = 32 * wv + 16 * n + lm;
      if (kout < NK) {
        const float bb = bvec[kout];
#pragma unroll
        for (int r = 0; r < 4; ++r) {
          const int row = m0 + 16 * i + 4 * lg + r;
          out[(size_t)row * NK + kout] = acc2[i][n][r] + bb;
        }
      }
    }
  }
}

// ---------------- fallback (round-1 kernel, used if ws too small) ----------------

#define A_PITCH1 520
#define BW_PITCH1 72
#define PHI_PITCH1 264

__global__ __launch_bounds__(256, 1)
void rbf_fused_v1(const float* __restrict__ x, const float* __restrict__ ctr,
                  const float* __restrict__ gamma_p, const float* __restrict__ W,
                  const float* __restrict__ bvec, float* __restrict__ out) {
  __shared__ alignas(16) short a_lds[64 * A_PITCH1];
  __shared__ alignas(16) short bw_lds[256 * BW_PITCH1];
  __shared__ alignas(16) short phi_lds[64 * PHI_PITCH1];
  __shared__ float xsq[64];
  __shared__ float csq[256];

  const int tid = threadIdx.x;
  const int lane = tid & 63;
  const int wv = tid >> 6;
  const int lm = lane & 15;
  const int lg = lane >> 4;
  const int m0 = blockIdx.x * 64;
  const float gma = gamma_p[0];

  {
    const int row = tid >> 2;
    const int seg = tid & 3;
    const float* xr = x + (size_t)(m0 + row) * NF + seg * 128;
    short* ar = a_lds + row * A_PITCH1 + seg * 128;
    float xp = 0.f;
#pragma unroll
    for (int i = 0; i < 32; ++i) {
      f4 v = ((const f4*)xr)[i];
      xp += v.x * v.x + v.y * v.y + v.z * v.z + v.w * v.w;
      short4v h;
      h.x = bf16t(v.x); h.y = bf16t(v.y); h.z = bf16t(v.z); h.w = bf16t(v.w);
      *(short4v*)(ar + i * 4) = h;
    }
    ((float*)phi_lds)[tid] = xp;
  }
  __syncthreads();
  if (tid < 64) {
    const float* pp = (const float*)phi_lds;
    xsq[tid] = pp[tid * 4] + pp[tid * 4 + 1] + pp[tid * 4 + 2] + pp[tid * 4 + 3];
  }

  const f4 fzero = {0.f, 0.f, 0.f, 0.f};
  f4 acc2[4][2];
#pragma unroll
  for (int i = 0; i < 4; ++i)
#pragma unroll
    for (int n = 0; n < 2; ++n) acc2[i][n] = fzero;

  const short* a_base = a_lds + lm * A_PITCH1 + lg * 8;
  const short* b_base = bw_lds + (64 * wv + lm) * BW_PITCH1 + lg * 8;
  const short* w_base = bw_lds + lm * BW_PITCH1 + lg * 8;
  const short* p_base = phi_lds + lm * PHI_PITCH1 + lg * 8;

  for (int chunk = 0; chunk < 4; ++chunk) {
    const int c0 = chunk * 256;
    f4 acc1[4][4];
#pragma unroll
    for (int i = 0; i < 4; ++i)
#pragma unroll
      for (int t = 0; t < 4; ++t) acc1[i][t] = fzero;
    float cpriv = 0.f;

    for (int kb = 0; kb < 8; ++kb) {
      __syncthreads();
      {
        const float* cr = ctr + (size_t)(c0 + tid) * NF + kb * 64;
        short* br = bw_lds + tid * BW_PITCH1;
#pragma unroll
        for (int i = 0; i < 16; ++i) {
          f4 v = ((const f4*)cr)[i];
          cpriv += v.x * v.x + v.y * v.y + v.z * v.z + v.w * v.w;
          short4v h;
          h.x = bf16t(v.x); h.y = bf16t(v.y); h.z = bf16t(v.z); h.w = bf16t(v.w);
          *(short4v*)(br + i * 4) = h;
        }
      }
      __syncthreads();
#pragma unroll
      for (int s = 0; s < 2; ++s) {
        short8 av[4], bv8[4];
#pragma unroll
        for (int i = 0; i < 4; ++i)
          av[i] = *(const short8*)(a_base + 16 * i * A_PITCH1 + 64 * kb + 32 * s);
#pragma unroll
        for (int t = 0; t < 4; ++t)
          bv8[t] = *(const short8*)(b_base + 16 * t * BW_PITCH1 + 32 * s);
#pragma unroll
        for (int i = 0; i < 4; ++i)
#pragma unroll
          for (int t = 0; t < 4; ++t)
            acc1[i][t] = __builtin_amdgcn_mfma_f32_16x16x32_bf16(
                av[i], bv8[t], acc1[i][t], 0, 0, 0);
      }
    }

    csq[tid] = cpriv;
    __syncthreads();

#pragma unroll
    for (int i = 0; i < 4; ++i) {
#pragma unroll
      for (int t = 0; t < 4; ++t) {
        const int colL = 64 * wv + 16 * t + lm;
        const float cs = csq[colL];
#pragma unroll
        for (int r = 0; r < 4; ++r) {
          const int rowL = 16 * i + 4 * lg + r;
          float d2 = xsq[rowL] + cs - 2.0f * acc1[i][t][r];
          d2 = fmaxf(d2, 0.f);
          const float ph = __expf(-gma * __fsqrt_rn(d2));
          phi_lds[rowL * PHI_PITCH1 + colL] = bf16t(ph);
        }
      }
    }

    for (int u = 0; u < 4; ++u) {
      __syncthreads();
      {
        const int row = tid >> 1;
        const int half = tid & 1;
        short* wr = bw_lds + row * BW_PITCH1 + half * 32;
        if (row < NK) {
          const float* ws = W + (size_t)row * NC + c0 + u * 64 + half * 32;
#pragma unroll
          for (int i = 0; i < 8; ++i) {
            f4 v = ((const f4*)ws)[i];
            short4v h;
            h.x = bf16t(v.x); h.y = bf16t(v.y); h.z = bf16t(v.z); h.w = bf16t(v.w);
            *(short4v*)(wr + i * 4) = h;
          }
        } else {
          const short4v zz = {0, 0, 0, 0};
#pragma unroll
          for (int i = 0; i < 8; ++i) *(short4v*)(wr + i * 4) = zz;
        }
      }
      __syncthreads();
#pragma unroll
      for (int s = 0; s < 2; ++s) {
        short8 pv[4], wv8[2];
#pragma unroll
        for (int i = 0; i < 4; ++i)
          pv[i] = *(const short8*)(p_base + 16 * i * PHI_PITCH1 + 64 * u + 32 * s);
#pragma unroll
        for (int n = 0; n < 2; ++n)
          wv8[n] = *(const short8*)(w_base + 16 * (2 * wv + n) * BW_PITCH1 + 32 * s);
#pragma unroll
        for (int i = 0; i < 4; ++i)
#pragma unroll
          for (int n = 0; n < 2; ++n)
            acc2[i][n] = __builtin_amdgcn_mfma_f32_16x16x32_bf16(
                pv[i], wv8[n], acc2[i][n], 0, 0, 0);
      }
    }
  }

#pragma unroll
  for (int i = 0; i < 4; ++i) {
#pragma unroll
    for (int n = 0; n < 2; ++n) {
      const int kout = 32 * wv + 16 * n + lm;
      if (kout < NK) {
        const float bb = bvec[kout];
#pragma unroll
        for (int r = 0; r < 4; ++r) {
          const int row = m0 + 16 * i + 4 * lg + r;
          out[(size_t)row * NK + kout] = acc2[i][n][r] + bb;
        }
      }
    }
  }
}

extern "C" void kernel_launch(void* const* d_in, const int* in_sizes, int n_in,
                              void* d_out, int out_size, void* d_ws, size_t ws_size,
                              hipStream_t stream) {
  (void)in_sizes; (void)n_in; (void)out_size;
  const float* x       = (const float*)d_in[0];
  const float* centers = (const float*)d_in[1];
  const float* gamma   = (const float*)d_in[2];
  const float* W       = (const float*)d_in[3];
  const float* b       = (const float*)d_in[4];
  float* out = (float*)d_out;

  if (ws_size >= (size_t)WS_NEED) {
    char* wsb = (char*)d_ws;
    char*  cbp  = wsb;                                  // 512KB fp8 centers
    float* csqp = (float*)(wsb + CB_BYTES);             // 1024 f32
    char*  wbp  = wsb + CB_BYTES + NC * 4;              // 256KB bf16 W
    prep_centers<<<dim3(32), dim3(256), 0, stream>>>(centers, cbp, csqp);
    prep_w<<<dim3(8), dim3(256), 0, stream>>>(W, wbp);
    rbf_main<<<dim3(NB / 32), dim3(256), 0, stream>>>(x, cbp, csqp, wbp, b,
                                                      gamma, out);
  } else {
    rbf_fused_v1<<<dim3(NB / 64), dim3(256), 0, stream>>>(x, centers, gamma, W,
                                                          b, out);
  }
}

// Round 6
// 116.019 us; speedup vs baseline: 1.0807x; 1.0807x over previous
//
#include <hip/hip_runtime.h>

// RBFNN fused, round 6: barrier-free K-loop — B/W fragments global->VGPR.
// out[B,K] = exp(-gamma * dist(x, centers)) @ W^T + b
// B=16384, F=512, C=1024, K=100.
//
// R5 evidence: 56 barrier intervals/block at ~1.9k cyc each vs ~700 floor;
// two interleaved blocks can't absorb the per-barrier vmcnt(0) drain. B/W
// frags have ZERO cross-wave sharing in our tiling, so LDS staging for them
// bought nothing but barriers. Now: prepass writes B (fp8) / W (bf16) in
// exact per-lane MFMA fragment order (frag*1024 + lane*16); the K-loop
// loads them global->VGPR (saddr + constant voffset, no VALU), explicitly
// register-double-buffered -> GEMM1 has NO barriers; compiler emits
// fine-grained vmcnt (the hipBLASLt pattern). LDS keeps only shared data:
// x tile (read-only after prologue) + phi (C/D->A transpose). 9 barriers
// total (1 prologue + 2/chunk). 32-row blocks, 512 blocks, 34KB LDS ->
// 2 resident blocks/CU cross-cover the few remaining drains.

#define NB 16384
#define NF 512
#define NC 1024
#define NK 100

#define A_PITCH 528   // bytes/row (512 fp8 + 16 pad)
#define P_PITCH 264   // shorts/row (256 bf16 + 8 pad)

#define CB_BYTES (NC * NF)      // 512KB fp8 centers, fragment-ordered
#define WB_BYTES (256 * 1024)   // 256KB bf16 W (100->128 kouts), frag-ordered
#define WS_NEED (CB_BYTES + NC * 4 + WB_BYTES)

typedef __attribute__((ext_vector_type(8))) short short8;
typedef __attribute__((ext_vector_type(4))) short short4v;
typedef __attribute__((ext_vector_type(4))) float f4;
typedef __attribute__((ext_vector_type(4))) unsigned int uint4v;
typedef __attribute__((ext_vector_type(2))) unsigned long ulong2v;
typedef unsigned short ushort;
typedef unsigned int uint;

__device__ __forceinline__ short bf16t(float f) {
  return (short)(__float_as_uint(f) >> 16);
}

__device__ __forceinline__ uint pk4_fp8(float a, float b, float c, float d) {
  uint r = __builtin_amdgcn_cvt_pk_fp8_f32(a, b, 0, false);
  return __builtin_amdgcn_cvt_pk_fp8_f32(c, d, r, true);
}

// ---------------- prepass kernels ----------------

// centers [1024,512] fp32 -> cb2 fp8 fragment-ordered + csq fp32.
// cb2 address ((c*8+kb)*16 + f)*1024 + lane*16, lane=(lg*16+lm):
//   16B = fp8 ctr[256c+16f+lm][kb*64 + lg*8 + (0..7)]  (low 8B, MFMA half .x)
//       ++ fp8 ctr[...][kb*64 + 32 + lg*8 + (0..7)]     (high 8B, half .y)
__global__ __launch_bounds__(256) void prep_centers(
    const float* __restrict__ ctr, char* __restrict__ cb,
    float* __restrict__ csq) {
  const int t = blockIdx.x * 256 + threadIdx.x;  // 0..8191
  const int cg = t >> 3;                          // center col 0..1023
  const int kb = t & 7;
  const f4* src = (const f4*)(ctr + (size_t)cg * NF + kb * 64);
  float f[64];
  float ss = 0.f;
#pragma unroll
  for (int i = 0; i < 16; ++i) {
    f4 v = src[i];
    f[4 * i] = v.x; f[4 * i + 1] = v.y; f[4 * i + 2] = v.z; f[4 * i + 3] = v.w;
    ss += v.x * v.x + v.y * v.y + v.z * v.z + v.w * v.w;
  }
  uint w[16];
#pragma unroll
  for (int m = 0; m < 16; ++m)
    w[m] = pk4_fp8(f[4 * m], f[4 * m + 1], f[4 * m + 2], f[4 * m + 3]);
  const int c = cg >> 8, fr = (cg >> 4) & 15, lm = cg & 15;
  char* base = cb + (size_t)((c * 8 + kb) * 16 + fr) * 1024 + lm * 16;
#pragma unroll
  for (int lg = 0; lg < 4; ++lg) {
    uint4v u = {w[2 * lg], w[2 * lg + 1], w[8 + 2 * lg], w[9 + 2 * lg]};
    *(uint4v*)(base + lg * 256) = u;  // lane = lg*16+lm -> +lg*256 bytes
  }
  ss += __shfl_down(ss, 4, 64);
  ss += __shfl_down(ss, 2, 64);
  ss += __shfl_down(ss, 1, 64);
  if (kb == 0) csq[cg] = ss;
}

// W [100,1024] fp32 -> wb2 bf16 fragment-ordered (kouts padded to 128).
// wb2 address ((c*8+ks)*8 + kf)*1024 + lane*16, lane=(lg*16+lm):
//   16B = bf16 W[16kf+lm][c*256 + ks*32 + lg*8 + (0..7)]
__global__ __launch_bounds__(256) void prep_w(const float* __restrict__ W,
                                              char* __restrict__ wb) {
  const int t = blockIdx.x * 256 + threadIdx.x;  // 0..511
  const int kout = t >> 2, c = t & 3;
  const int kf = kout >> 4, lm = kout & 15;
#pragma unroll
  for (int ks = 0; ks < 8; ++ks) {
#pragma unroll
    for (int lg = 0; lg < 4; ++lg) {
      short4v h0 = {0, 0, 0, 0}, h1 = {0, 0, 0, 0};
      if (kout < NK) {
        const float* src = W + (size_t)kout * NC + c * 256 + ks * 32 + lg * 8;
        f4 v0 = ((const f4*)src)[0], v1 = ((const f4*)src)[1];
        h0.x = bf16t(v0.x); h0.y = bf16t(v0.y); h0.z = bf16t(v0.z); h0.w = bf16t(v0.w);
        h1.x = bf16t(v1.x); h1.y = bf16t(v1.y); h1.z = bf16t(v1.z); h1.w = bf16t(v1.w);
      }
      char* dst = wb + (size_t)((c * 8 + ks) * 8 + kf) * 1024 +
                  (lg * 16 + lm) * 16;
      *(short4v*)dst = h0;
      *(short4v*)(dst + 8) = h1;
    }
  }
}

// ---------------- main kernel ----------------

__global__ __launch_bounds__(256, 2)
void rbf_main(const float* __restrict__ x, const char* __restrict__ cb2,
              const float* __restrict__ csqp, const char* __restrict__ wb2,
              const float* __restrict__ bvec, const float* __restrict__ gamma_p,
              float* __restrict__ out) {
  __shared__ alignas(16) char a_lds[32 * A_PITCH];     // 16896 B, x fp8
  __shared__ alignas(16) short phi_lds[32 * P_PITCH];  // 16896 B, phi bf16
  __shared__ float xsq[32];

  const int tid = threadIdx.x;
  const int lane = tid & 63;
  const int wv = tid >> 6;   // 0..3
  const int lm = lane & 15;
  const int lg = lane >> 4;
  const int m0 = blockIdx.x * 32;
  const float gma = gamma_p[0];
  const int laneoff = lane << 4;

  // ---- prologue: stage x tile (fp32->fp8 fragment-paired) + xsq ----
  {
    const int row = tid >> 3;   // 0..31
    const int seg = tid & 7;    // k block of 64
    const f4* xr = (const f4*)(x + (size_t)(m0 + row) * NF + seg * 64);
    float f[64];
    float ss = 0.f;
#pragma unroll
    for (int i = 0; i < 16; ++i) {
      f4 v = xr[i];
      f[4 * i] = v.x; f[4 * i + 1] = v.y; f[4 * i + 2] = v.z; f[4 * i + 3] = v.w;
      ss += v.x * v.x + v.y * v.y + v.z * v.z + v.w * v.w;
    }
    uint w[16];
#pragma unroll
    for (int m = 0; m < 16; ++m)
      w[m] = pk4_fp8(f[4 * m], f[4 * m + 1], f[4 * m + 2], f[4 * m + 3]);
    char* ar = a_lds + row * A_PITCH + seg * 64;
#pragma unroll
    for (int l2 = 0; l2 < 4; ++l2) {
      uint4v u = {w[2 * l2], w[2 * l2 + 1], w[8 + 2 * l2], w[9 + 2 * l2]};
      *(uint4v*)(ar + l2 * 16) = u;
    }
    ((float*)phi_lds)[tid] = ss;  // scratch partials
  }
  __syncthreads();
  if (tid < 32) {
    const float* pp = (const float*)phi_lds + 8 * tid;
    xsq[tid] = pp[0] + pp[1] + pp[2] + pp[3] + pp[4] + pp[5] + pp[6] + pp[7];
  }  // consumed after chunk-0's pre-epilogue barrier

  const f4 fzero = {0.f, 0.f, 0.f, 0.f};
  f4 acc2[2][2];
#pragma unroll
  for (int i = 0; i < 2; ++i)
#pragma unroll
    for (int n = 0; n < 2; ++n) acc2[i][n] = fzero;

  for (int c = 0; c < 4; ++c) {
    float csr[4];
#pragma unroll
    for (int t = 0; t < 4; ++t)
      csr[t] = csqp[c * 256 + 16 * (wv + 4 * t) + lm];

    f4 acc1[2][4];
#pragma unroll
    for (int i = 0; i < 2; ++i)
#pragma unroll
      for (int t = 0; t < 4; ++t) acc1[i][t] = fzero;

    // ---- GEMM1: 8 k=64 stages, NO barriers; B frags global->VGPR ----
    const char* bb = cb2 + (size_t)c * 131072;  // 8 stages * 16 frags * 1KB
    ulong2v bp[2][4];
#pragma unroll
    for (int t = 0; t < 4; ++t)
      bp[0][t] = *(const ulong2v*)(bb + ((wv + 4 * t) << 10) + laneoff);
#pragma unroll
    for (int kb = 0; kb < 8; ++kb) {
      const int cur = kb & 1;
      if (kb < 7) {
#pragma unroll
        for (int t = 0; t < 4; ++t)
          bp[cur ^ 1][t] = *(const ulong2v*)(
              bb + (((kb + 1) * 16 + wv + 4 * t) << 10) + laneoff);
      }
      ulong2v a2[2];
#pragma unroll
      for (int i = 0; i < 2; ++i)
        a2[i] = *(const ulong2v*)(a_lds + (16 * i + lm) * A_PITCH + kb * 64 +
                                  lg * 16);
#pragma unroll
      for (int i = 0; i < 2; ++i)
#pragma unroll
        for (int t = 0; t < 4; ++t)
          acc1[i][t] = __builtin_amdgcn_mfma_f32_16x16x32_fp8_fp8(
              (long)a2[i].x, (long)bp[cur][t].x, acc1[i][t], 0, 0, 0);
#pragma unroll
      for (int i = 0; i < 2; ++i)
#pragma unroll
        for (int t = 0; t < 4; ++t)
          acc1[i][t] = __builtin_amdgcn_mfma_f32_16x16x32_fp8_fp8(
              (long)a2[i].y, (long)bp[cur][t].y, acc1[i][t], 0, 0, 0);
    }

    // preload first W frags BEFORE the barrier (drain covered by barrier)
    const char* wwb = wb2 + (size_t)c * 65536;  // 8 ks * 8 kf * 1KB
    short8 wp[2][2];
#pragma unroll
    for (int n = 0; n < 2; ++n)
      wp[0][n] = *(const short8*)(wwb + ((2 * wv + n) << 10) + laneoff);

    __syncthreads();  // c>0: all waves done reading phi(c-1); c==0: xsq ready

    // ---- epilogue: phi = exp(-gamma*dist) -> LDS (A layout) ----
#pragma unroll
    for (int t = 0; t < 4; ++t) {
      const float cs = csr[t];
      const int colh = 16 * (wv + 4 * t) + lm;
#pragma unroll
      for (int i = 0; i < 2; ++i) {
#pragma unroll
        for (int r = 0; r < 4; ++r) {
          const int rowL = 16 * i + 4 * lg + r;
          float d2 = xsq[rowL] + cs - 2.0f * acc1[i][t][r];
          d2 = fmaxf(d2, 0.f);
          const float ph = __expf(-gma * __builtin_amdgcn_sqrtf(d2));
          phi_lds[rowL * P_PITCH + colh] = bf16t(ph);
        }
      }
    }
    __syncthreads();  // phi published

    // ---- GEMM2: 8 k=32 steps, NO barriers; W frags global->VGPR ----
#pragma unroll
    for (int ks = 0; ks < 8; ++ks) {
      const int cur = ks & 1;
      if (ks < 7) {
#pragma unroll
        for (int n = 0; n < 2; ++n)
          wp[cur ^ 1][n] = *(const short8*)(
              wwb + (((ks + 1) * 8 + 2 * wv + n) << 10) + laneoff);
      }
      short8 pv[2];
#pragma unroll
      for (int i = 0; i < 2; ++i)
        pv[i] = *(const short8*)(phi_lds + (16 * i + lm) * P_PITCH + ks * 32 +
                                 lg * 8);
#pragma unroll
      for (int i = 0; i < 2; ++i)
#pragma unroll
        for (int n = 0; n < 2; ++n)
          acc2[i][n] = __builtin_amdgcn_mfma_f32_16x16x32_bf16(
              pv[i], wp[cur][n], acc2[i][n], 0, 0, 0);
    }
  }

  // ---- out = acc2 + b, kout = 32wv + 16n + lm < 100 ----
#pragma unroll
  for (int i = 0; i < 2; ++i) {
#pragma unroll
    for (int n = 0; n < 2; ++n) {
      const int kout = 32 * wv + 16 * n + lm;
      if (kout < NK) {
        const float bb2 = bvec[kout];
#pragma unroll
        for (int r = 0; r < 4; ++r) {
          const int row = m0 + 16 * i + 4 * lg + r;
          out[(size_t)row * NK + kout] = acc2[i][n][r] + bb2;
        }
      }
    }
  }
}

// ---------------- fallback (round-1 kernel, used if ws too small) ----------------

#define A_PITCH1 520
#define BW_PITCH1 72
#define PHI_PITCH1 264

__global__ __launch_bounds__(256, 1)
void rbf_fused_v1(const float* __restrict__ x, const float* __restrict__ ctr,
                  const float* __restrict__ gamma_p, const float* __restrict__ W,
                  const float* __restrict__ bvec, float* __restrict__ out) {
  __shared__ alignas(16) short a_lds[64 * A_PITCH1];
  __shared__ alignas(16) short bw_lds[256 * BW_PITCH1];
  __shared__ alignas(16) short phi_lds[64 * PHI_PITCH1];
  __shared__ float xsq[64];
  __shared__ float csq[256];

  const int tid = threadIdx.x;
  const int lane = tid & 63;
  const int wv = tid >> 6;
  const int lm = lane & 15;
  const int lg = lane >> 4;
  const int m0 = blockIdx.x * 64;
  const float gma = gamma_p[0];

  {
    const int row = tid >> 2;
    const int seg = tid & 3;
    const float* xr = x + (size_t)(m0 + row) * NF + seg * 128;
    short* ar = a_lds + row * A_PITCH1 + seg * 128;
    float xp = 0.f;
#pragma unroll
    for (int i = 0; i < 32; ++i) {
      f4 v = ((const f4*)xr)[i];
      xp += v.x * v.x + v.y * v.y + v.z * v.z + v.w * v.w;
      short4v h;
      h.x = bf16t(v.x); h.y = bf16t(v.y); h.z = bf16t(v.z); h.w = bf16t(v.w);
      *(short4v*)(ar + i * 4) = h;
    }
    ((float*)phi_lds)[tid] = xp;
  }
  __syncthreads();
  if (tid < 64) {
    const float* pp = (const float*)phi_lds;
    xsq[tid] = pp[tid * 4] + pp[tid * 4 + 1] + pp[tid * 4 + 2] + pp[tid * 4 + 3];
  }

  const f4 fzero = {0.f, 0.f, 0.f, 0.f};
  f4 acc2[4][2];
#pragma unroll
  for (int i = 0; i < 4; ++i)
#pragma unroll
    for (int n = 0; n < 2; ++n) acc2[i][n] = fzero;

  const short* a_base = a_lds + lm * A_PITCH1 + lg * 8;
  const short* b_base = bw_lds + (64 * wv + lm) * BW_PITCH1 + lg * 8;
  const short* w_base = bw_lds + lm * BW_PITCH1 + lg * 8;
  const short* p_base = phi_lds + lm * PHI_PITCH1 + lg * 8;

  for (int chunk = 0; chunk < 4; ++chunk) {
    const int c0 = chunk * 256;
    f4 acc1[4][4];
#pragma unroll
    for (int i = 0; i < 4; ++i)
#pragma unroll
      for (int t = 0; t < 4; ++t) acc1[i][t] = fzero;
    float cpriv = 0.f;

    for (int kb = 0; kb < 8; ++kb) {
      __syncthreads();
      {
        const float* cr = ctr + (size_t)(c0 + tid) * NF + kb * 64;
        short* br = bw_lds + tid * BW_PITCH1;
#pragma unroll
        for (int i = 0; i < 16; ++i) {
          f4 v = ((const f4*)cr)[i];
          cpriv += v.x * v.x + v.y * v.y + v.z * v.z + v.w * v.w;
          short4v h;
          h.x = bf16t(v.x); h.y = bf16t(v.y); h.z = bf16t(v.z); h.w = bf16t(v.w);
          *(short4v*)(br + i * 4) = h;
        }
      }
      __syncthreads();
#pragma unroll
      for (int s = 0; s < 2; ++s) {
        short8 av[4], bv8[4];
#pragma unroll
        for (int i = 0; i < 4; ++i)
          av[i] = *(const short8*)(a_base + 16 * i * A_PITCH1 + 64 * kb + 32 * s);
#pragma unroll
        for (int t = 0; t < 4; ++t)
          bv8[t] = *(const short8*)(b_base + 16 * t * BW_PITCH1 + 32 * s);
#pragma unroll
        for (int i = 0; i < 4; ++i)
#pragma unroll
          for (int t = 0; t < 4; ++t)
            acc1[i][t] = __builtin_amdgcn_mfma_f32_16x16x32_bf16(
                av[i], bv8[t], acc1[i][t], 0, 0, 0);
      }
    }

    csq[tid] = cpriv;
    __syncthreads();

#pragma unroll
    for (int i = 0; i < 4; ++i) {
#pragma unroll
      for (int t = 0; t < 4; ++t) {
        const int colL = 64 * wv + 16 * t + lm;
        const float cs = csq[colL];
#pragma unroll
        for (int r = 0; r < 4; ++r) {
          const int rowL = 16 * i + 4 * lg + r;
          float d2 = xsq[rowL] + cs - 2.0f * acc1[i][t][r];
          d2 = fmaxf(d2, 0.f);
          const float ph = __expf(-gma * __fsqrt_rn(d2));
          phi_lds[rowL * PHI_PITCH1 + colL] = bf16t(ph);
        }
      }
    }

    for (int u = 0; u < 4; ++u) {
      __syncthreads();
      {
        const int row = tid >> 1;
        const int half = tid & 1;
        short* wr = bw_lds + row * BW_PITCH1 + half * 32;
        if (row < NK) {
          const float* ws = W + (size_t)row * NC + c0 + u * 64 + half * 32;
#pragma unroll
          for (int i = 0; i < 8; ++i) {
            f4 v = ((const f4*)ws)[i];
            short4v h;
            h.x = bf16t(v.x); h.y = bf16t(v.y); h.z = bf16t(v.z); h.w = bf16t(v.w);
            *(short4v*)(wr + i * 4) = h;
          }
        } else {
          const short4v zz = {0, 0, 0, 0};
#pragma unroll
          for (int i = 0; i < 8; ++i) *(short4v*)(wr + i * 4) = zz;
        }
      }
      __syncthreads();
#pragma unroll
      for (int s = 0; s < 2; ++s) {
        short8 pv[4], wv8[2];
#pragma unroll
        for (int i = 0; i < 4; ++i)
          pv[i] = *(const short8*)(p_base + 16 * i * PHI_PITCH1 + 64 * u + 32 * s);
#pragma unroll
        for (int n = 0; n < 2; ++n)
          wv8[n] = *(const short8*)(w_base + 16 * (2 * wv + n) * BW_PITCH1 + 32 * s);
#pragma unroll
        for (int i = 0; i < 4; ++i)
#pragma unroll
          for (int n = 0; n < 2; ++n)
            acc2[i][n] = __builtin_amdgcn_mfma_f32_16x16x32_bf16(
                pv[i], wv8[n], acc2[i][n], 0, 0, 0);
      }
    }
  }

#pragma unroll
  for (int i = 0; i < 4; ++i) {
#pragma unroll
    for (int n = 0; n < 2; ++n) {
      const int kout = 32 * wv + 16 * n + lm;
      if (kout < NK) {
        const float bb = bvec[kout];
#pragma unroll
        for (int r = 0; r < 4; ++r) {
          const int row = m0 + 16 * i + 4 * lg + r;
          out[(size_t)row * NK + kout] = acc2[i][n][r] + bb;
        }
      }
    }
  }
}

extern "C" void kernel_launch(void* const* d_in, const int* in_sizes, int n_in,
                              void* d_out, int out_size, void* d_ws, size_t ws_size,
                              hipStream_t stream) {
  (void)in_sizes; (void)n_in; (void)out_size;
  const float* x       = (const float*)d_in[0];
  const float* centers = (const float*)d_in[1];
  const float* gamma   = (const float*)d_in[2];
  const float* W       = (const float*)d_in[3];
  const float* b       = (const float*)d_in[4];
  float* out = (float*)d_out;

  if (ws_size >= (size_t)WS_NEED) {
    char* wsb = (char*)d_ws;
    char*  cbp  = wsb;                                  // 512KB fp8 centers
    float* csqp = (float*)(wsb + CB_BYTES);             // 1024 f32
    char*  wbp  = wsb + CB_BYTES + NC * 4;              // 256KB bf16 W
    prep_centers<<<dim3(32), dim3(256), 0, stream>>>(centers, cbp, csqp);
    prep_w<<<dim3(2), dim3(256), 0, stream>>>(W, wbp);
    rbf_main<<<dim3(NB / 32), dim3(256), 0, stream>>>(x, cbp, csqp, wbp, b,
                                                      gamma, out);
  } else {
    rbf_fused_v1<<<dim3(NB / 64), dim3(256), 0, stream>>>(x, centers, gamma, W,
                                                          b, out);
  }
}

// Round 7
// 112.416 us; speedup vs baseline: 1.1153x; 1.0320x over previous
//
#include <hip/hip_runtime.h>

// RBFNN fused, round 7: R6 barrier-free skeleton + three exposure fixes.
// out[B,K] = exp(-gamma * dist(x, centers)) @ W^T + b
// B=16384, F=512, C=1024, K=100.
//
// R6 ladder: 140->53->49->44->~35us. Remaining exposure: (a) 9 barrier
// drains with preloads sitting exposed right after; (b) G1 depth-1 reg dbuf
// covers ~77-150cyc < ~200-300cyc L2 latency; (c) G2 depth-1 W prefetch
// covers ~38cyc/stage. Fixes:
//  1. phi double-buffer -> ONE barrier per chunk (6 total). Race audit:
//     epilogue(c) writes phi[c&1]; slowest wave past barrier(c-1) reads
//     phi[(c-1)&1] in G2(c-1) -- different buffer; a wave cannot reach
//     epilogue(c+1) without passing barrier(c) which all waves reach only
//     after their G2(c-1).
//  2. B frags ring-3 (prefetch distance 2 >= L2 latency); next chunk's
//     stages 0,1 hoisted BEFORE the barrier -> drained for free.
//  3. ALL 8 W stage-pairs preloaded before the barrier (64 VGPRs; ~190
//     total, 2 waves/SIMD keeps) -> G2 has zero global stalls.
//  4. prep kernels merged into one launch.
// LDS ~51KB -> 2 blocks/CU (512 blocks, 256 thr).

#define NB 16384
#define NF 512
#define NC 1024
#define NK 100

#define A_PITCH 528   // bytes/row (512 fp8 + 16 pad)
#define P_PITCH 264   // shorts/row (256 bf16 + 8 pad)

#define CB_BYTES (NC * NF)      // 512KB fp8 centers, fragment-ordered
#define WB_BYTES (256 * 1024)   // 256KB bf16 W (100->128 kouts), frag-ordered
#define WS_NEED (CB_BYTES + NC * 4 + WB_BYTES)

typedef __attribute__((ext_vector_type(8))) short short8;
typedef __attribute__((ext_vector_type(4))) short short4v;
typedef __attribute__((ext_vector_type(4))) float f4;
typedef __attribute__((ext_vector_type(4))) unsigned int uint4v;
typedef __attribute__((ext_vector_type(2))) unsigned long ulong2v;
typedef unsigned short ushort;
typedef unsigned int uint;

__device__ __forceinline__ short bf16t(float f) {
  return (short)(__float_as_uint(f) >> 16);
}

__device__ __forceinline__ uint pk4_fp8(float a, float b, float c, float d) {
  uint r = __builtin_amdgcn_cvt_pk_fp8_f32(a, b, 0, false);
  return __builtin_amdgcn_cvt_pk_fp8_f32(c, d, r, true);
}

// ---------------- merged prepass ----------------
// blocks 0..31: centers [1024,512] fp32 -> cb fp8 fragment-ordered + csq.
//   cb addr ((c*8+kb)*16 + f)*1024 + lane*16, lane=lg*16+lm:
//   low 8B = fp8 ctr[256c+16f+lm][kb*64+lg*8+..], high 8B = same +32.
// blocks 32..33: W [100,1024] fp32 -> wb bf16 fragment-ordered, 128 kouts.
//   wb addr ((c*8+ks)*8 + kf)*1024 + lane*16 = bf16 W[16kf+lm][c*256+ks*32+lg*8+..]
__global__ __launch_bounds__(256) void prep_all(
    const float* __restrict__ ctr, const float* __restrict__ W,
    char* __restrict__ cb, float* __restrict__ csq, char* __restrict__ wb) {
  if (blockIdx.x < 32) {
    const int t = blockIdx.x * 256 + threadIdx.x;  // 0..8191
    const int cg = t >> 3;                          // center row 0..1023
    const int kb = t & 7;
    const f4* src = (const f4*)(ctr + (size_t)cg * NF + kb * 64);
    float f[64];
    float ss = 0.f;
#pragma unroll
    for (int i = 0; i < 16; ++i) {
      f4 v = src[i];
      f[4 * i] = v.x; f[4 * i + 1] = v.y; f[4 * i + 2] = v.z; f[4 * i + 3] = v.w;
      ss += v.x * v.x + v.y * v.y + v.z * v.z + v.w * v.w;
    }
    uint w[16];
#pragma unroll
    for (int m = 0; m < 16; ++m)
      w[m] = pk4_fp8(f[4 * m], f[4 * m + 1], f[4 * m + 2], f[4 * m + 3]);
    const int c = cg >> 8, fr = (cg >> 4) & 15, lm = cg & 15;
    char* base = cb + (size_t)((c * 8 + kb) * 16 + fr) * 1024 + lm * 16;
#pragma unroll
    for (int lg = 0; lg < 4; ++lg) {
      uint4v u = {w[2 * lg], w[2 * lg + 1], w[8 + 2 * lg], w[9 + 2 * lg]};
      *(uint4v*)(base + lg * 256) = u;
    }
    ss += __shfl_down(ss, 4, 64);
    ss += __shfl_down(ss, 2, 64);
    ss += __shfl_down(ss, 1, 64);
    if (kb == 0) csq[cg] = ss;
  } else {
    const int t = (blockIdx.x - 32) * 256 + threadIdx.x;  // 0..511
    const int kout = t >> 2, c = t & 3;
    const int kf = kout >> 4, lm = kout & 15;
#pragma unroll
    for (int ks = 0; ks < 8; ++ks) {
#pragma unroll
      for (int lg = 0; lg < 4; ++lg) {
        short4v h0 = {0, 0, 0, 0}, h1 = {0, 0, 0, 0};
        if (kout < NK) {
          const float* src = W + (size_t)kout * NC + c * 256 + ks * 32 + lg * 8;
          f4 v0 = ((const f4*)src)[0], v1 = ((const f4*)src)[1];
          h0.x = bf16t(v0.x); h0.y = bf16t(v0.y); h0.z = bf16t(v0.z); h0.w = bf16t(v0.w);
          h1.x = bf16t(v1.x); h1.y = bf16t(v1.y); h1.z = bf16t(v1.z); h1.w = bf16t(v1.w);
        }
        char* dst = wb + (size_t)((c * 8 + ks) * 8 + kf) * 1024 +
                    (lg * 16 + lm) * 16;
        *(short4v*)dst = h0;
        *(short4v*)(dst + 8) = h1;
      }
    }
  }
}

// ---------------- main kernel ----------------

__global__ __launch_bounds__(256, 2)
void rbf_main(const float* __restrict__ x, const char* __restrict__ cb2,
              const float* __restrict__ csqp, const char* __restrict__ wb2,
              const float* __restrict__ bvec, const float* __restrict__ gamma_p,
              float* __restrict__ out) {
  __shared__ alignas(16) char a_lds[32 * A_PITCH];        // 16896 B, x fp8
  __shared__ alignas(16) short phi_lds[2][32 * P_PITCH];  // 33792 B, phi dbuf
  __shared__ float xsq[32];

  const int tid = threadIdx.x;
  const int lane = tid & 63;
  const int wv = tid >> 6;   // 0..3
  const int lm = lane & 15;
  const int lg = lane >> 4;
  const int m0 = blockIdx.x * 32;
  const float gma = gamma_p[0];
  const int laneoff = lane << 4;

  // ---- prologue: stage x tile (fp32->fp8 fragment-paired) + xsq ----
  {
    const int row = tid >> 3;   // 0..31
    const int seg = tid & 7;    // k block of 64
    const f4* xr = (const f4*)(x + (size_t)(m0 + row) * NF + seg * 64);
    float f[64];
    float ss = 0.f;
#pragma unroll
    for (int i = 0; i < 16; ++i) {
      f4 v = xr[i];
      f[4 * i] = v.x; f[4 * i + 1] = v.y; f[4 * i + 2] = v.z; f[4 * i + 3] = v.w;
      ss += v.x * v.x + v.y * v.y + v.z * v.z + v.w * v.w;
    }
    uint w[16];
#pragma unroll
    for (int m = 0; m < 16; ++m)
      w[m] = pk4_fp8(f[4 * m], f[4 * m + 1], f[4 * m + 2], f[4 * m + 3]);
    char* ar = a_lds + row * A_PITCH + seg * 64;
#pragma unroll
    for (int l2 = 0; l2 < 4; ++l2) {
      uint4v u = {w[2 * l2], w[2 * l2 + 1], w[8 + 2 * l2], w[9 + 2 * l2]};
      *(uint4v*)(ar + l2 * 16) = u;
    }
    ((float*)phi_lds[0])[tid] = ss;  // scratch partials (consumed pre-E0)
  }

  // B frag ring buffer; preload chunk-0 stages 0,1 (drain at barrier #1/#2)
  ulong2v bp[3][4];
#pragma unroll
  for (int t = 0; t < 4; ++t) {
    bp[0][t] = *(const ulong2v*)(cb2 + ((wv + 4 * t) << 10) + laneoff);
    bp[1][t] = *(const ulong2v*)(cb2 + ((16 + wv + 4 * t) << 10) + laneoff);
  }

  __syncthreads();  // publishes a_lds + partials
  if (tid < 32) {
    const float* pp = (const float*)phi_lds[0] + 8 * tid;
    xsq[tid] = pp[0] + pp[1] + pp[2] + pp[3] + pp[4] + pp[5] + pp[6] + pp[7];
  }
  __syncthreads();  // publishes xsq

  const f4 fzero = {0.f, 0.f, 0.f, 0.f};
  f4 acc2[2][2];
#pragma unroll
  for (int i = 0; i < 2; ++i)
#pragma unroll
    for (int n = 0; n < 2; ++n) acc2[i][n] = fzero;

  for (int c = 0; c < 4; ++c) {
    float csr[4];
#pragma unroll
    for (int t = 0; t < 4; ++t)
      csr[t] = csqp[c * 256 + 16 * (wv + 4 * t) + lm];

    f4 acc1[2][4];
#pragma unroll
    for (int i = 0; i < 2; ++i)
#pragma unroll
      for (int t = 0; t < 4; ++t) acc1[i][t] = fzero;

    // ---- GEMM1: 8 k=64 stages, no barriers, B ring-3 (distance 2) ----
    const char* bb = cb2 + (size_t)c * 131072;
#pragma unroll
    for (int kb = 0; kb < 8; ++kb) {
      if (kb < 6) {
#pragma unroll
        for (int t = 0; t < 4; ++t)
          bp[(kb + 2) % 3][t] = *(const ulong2v*)(
              bb + (((kb + 2) * 16 + wv + 4 * t) << 10) + laneoff);
      }
      ulong2v a2[2];
#pragma unroll
      for (int i = 0; i < 2; ++i)
        a2[i] = *(const ulong2v*)(a_lds + (16 * i + lm) * A_PITCH + kb * 64 +
                                  lg * 16);
      const int cur = kb % 3;
#pragma unroll
      for (int i = 0; i < 2; ++i)
#pragma unroll
        for (int t = 0; t < 4; ++t)
          acc1[i][t] = __builtin_amdgcn_mfma_f32_16x16x32_fp8_fp8(
              (long)a2[i].x, (long)bp[cur][t].x, acc1[i][t], 0, 0, 0);
#pragma unroll
      for (int i = 0; i < 2; ++i)
#pragma unroll
        for (int t = 0; t < 4; ++t)
          acc1[i][t] = __builtin_amdgcn_mfma_f32_16x16x32_fp8_fp8(
              (long)a2[i].y, (long)bp[cur][t].y, acc1[i][t], 0, 0, 0);
    }

    // ---- preloads (in flight across epilogue; drained by the barrier) ----
    const char* wwb = wb2 + (size_t)c * 65536;
    short8 wp[8][2];
#pragma unroll
    for (int ks = 0; ks < 8; ++ks)
#pragma unroll
      for (int n = 0; n < 2; ++n)
        wp[ks][n] = *(const short8*)(wwb + ((ks * 8 + 2 * wv + n) << 10) +
                                     laneoff);
    if (c < 3) {
      const char* bbn = cb2 + (size_t)(c + 1) * 131072;
#pragma unroll
      for (int t = 0; t < 4; ++t) {
        bp[0][t] = *(const ulong2v*)(bbn + ((wv + 4 * t) << 10) + laneoff);
        bp[1][t] = *(const ulong2v*)(bbn + ((16 + wv + 4 * t) << 10) + laneoff);
      }
    }

    // ---- epilogue: phi = exp(-gamma*dist) -> phi_lds[c&1] (A layout) ----
    short* phb = phi_lds[c & 1];
#pragma unroll
    for (int t = 0; t < 4; ++t) {
      const float cs = csr[t];
      const int colh = 16 * (wv + 4 * t) + lm;
#pragma unroll
      for (int i = 0; i < 2; ++i) {
#pragma unroll
        for (int r = 0; r < 4; ++r) {
          const int rowL = 16 * i + 4 * lg + r;
          float d2 = xsq[rowL] + cs - 2.0f * acc1[i][t][r];
          d2 = fmaxf(d2, 0.f);
          const float ph = __expf(-gma * __builtin_amdgcn_sqrtf(d2));
          phb[rowL * P_PITCH + colh] = bf16t(ph);
        }
      }
    }
    __syncthreads();  // the chunk's ONLY barrier: publishes phi, drains loads

    // ---- GEMM2: 8 k=32 steps, zero global stalls (W fully preloaded) ----
#pragma unroll
    for (int ks = 0; ks < 8; ++ks) {
      short8 pv[2];
#pragma unroll
      for (int i = 0; i < 2; ++i)
        pv[i] = *(const short8*)(phb + (16 * i + lm) * P_PITCH + ks * 32 +
                                 lg * 8);
#pragma unroll
      for (int i = 0; i < 2; ++i)
#pragma unroll
        for (int n = 0; n < 2; ++n)
          acc2[i][n] = __builtin_amdgcn_mfma_f32_16x16x32_bf16(
              pv[i], wp[ks][n], acc2[i][n], 0, 0, 0);
    }
  }

  // ---- out = acc2 + b, kout = 32wv + 16n + lm < 100 ----
#pragma unroll
  for (int i = 0; i < 2; ++i) {
#pragma unroll
    for (int n = 0; n < 2; ++n) {
      const int kout = 32 * wv + 16 * n + lm;
      if (kout < NK) {
        const float bb2 = bvec[kout];
#pragma unroll
        for (int r = 0; r < 4; ++r) {
          const int row = m0 + 16 * i + 4 * lg + r;
          out[(size_t)row * NK + kout] = acc2[i][n][r] + bb2;
        }
      }
    }
  }
}

// ---------------- fallback (round-1 kernel, used if ws too small) ----------------

#define A_PITCH1 520
#define BW_PITCH1 72
#define PHI_PITCH1 264

__global__ __launch_bounds__(256, 1)
void rbf_fused_v1(const float* __restrict__ x, const float* __restrict__ ctr,
                  const float* __restrict__ gamma_p, const float* __restrict__ W,
                  const float* __restrict__ bvec, float* __restrict__ out) {
  __shared__ alignas(16) short a_lds[64 * A_PITCH1];
  __shared__ alignas(16) short bw_lds[256 * BW_PITCH1];
  __shared__ alignas(16) short phi_lds[64 * PHI_PITCH1];
  __shared__ float xsq[64];
  __shared__ float csq[256];

  const int tid = threadIdx.x;
  const int lane = tid & 63;
  const int wv = tid >> 6;
  const int lm = lane & 15;
  const int lg = lane >> 4;
  const int m0 = blockIdx.x * 64;
  const float gma = gamma_p[0];

  {
    const int row = tid >> 2;
    const int seg = tid & 3;
    const float* xr = x + (size_t)(m0 + row) * NF + seg * 128;
    short* ar = a_lds + row * A_PITCH1 + seg * 128;
    float xp = 0.f;
#pragma unroll
    for (int i = 0; i < 32; ++i) {
      f4 v = ((const f4*)xr)[i];
      xp += v.x * v.x + v.y * v.y + v.z * v.z + v.w * v.w;
      short4v h;
      h.x = bf16t(v.x); h.y = bf16t(v.y); h.z = bf16t(v.z); h.w = bf16t(v.w);
      *(short4v*)(ar + i * 4) = h;
    }
    ((float*)phi_lds)[tid] = xp;
  }
  __syncthreads();
  if (tid < 64) {
    const float* pp = (const float*)phi_lds;
    xsq[tid] = pp[tid * 4] + pp[tid * 4 + 1] + pp[tid * 4 + 2] + pp[tid * 4 + 3];
  }

  const f4 fzero = {0.f, 0.f, 0.f, 0.f};
  f4 acc2[4][2];
#pragma unroll
  for (int i = 0; i < 4; ++i)
#pragma unroll
    for (int n = 0; n < 2; ++n) acc2[i][n] = fzero;

  const short* a_base = a_lds + lm * A_PITCH1 + lg * 8;
  const short* b_base = bw_lds + (64 * wv + lm) * BW_PITCH1 + lg * 8;
  const short* w_base = bw_lds + lm * BW_PITCH1 + lg * 8;
  const short* p_base = phi_lds + lm * PHI_PITCH1 + lg * 8;

  for (int chunk = 0; chunk < 4; ++chunk) {
    const int c0 = chunk * 256;
    f4 acc1[4][4];
#pragma unroll
    for (int i = 0; i < 4; ++i)
#pragma unroll
      for (int t = 0; t < 4; ++t) acc1[i][t] = fzero;
    float cpriv = 0.f;

    for (int kb = 0; kb < 8; ++kb) {
      __syncthreads();
      {
        const float* cr = ctr + (size_t)(c0 + tid) * NF + kb * 64;
        short* br = bw_lds + tid * BW_PITCH1;
#pragma unroll
        for (int i = 0; i < 16; ++i) {
          f4 v = ((const f4*)cr)[i];
          cpriv += v.x * v.x + v.y * v.y + v.z * v.z + v.w * v.w;
          short4v h;
          h.x = bf16t(v.x); h.y = bf16t(v.y); h.z = bf16t(v.z); h.w = bf16t(v.w);
          *(short4v*)(br + i * 4) = h;
        }
      }
      __syncthreads();
#pragma unroll
      for (int s = 0; s < 2; ++s) {
        short8 av[4], bv8[4];
#pragma unroll
        for (int i = 0; i < 4; ++i)
          av[i] = *(const short8*)(a_base + 16 * i * A_PITCH1 + 64 * kb + 32 * s);
#pragma unroll
        for (int t = 0; t < 4; ++t)
          bv8[t] = *(const short8*)(b_base + 16 * t * BW_PITCH1 + 32 * s);
#pragma unroll
        for (int i = 0; i < 4; ++i)
#pragma unroll
          for (int t = 0; t < 4; ++t)
            acc1[i][t] = __builtin_amdgcn_mfma_f32_16x16x32_bf16(
                av[i], bv8[t], acc1[i][t], 0, 0, 0);
      }
    }

    csq[tid] = cpriv;
    __syncthreads();

#pragma unroll
    for (int i = 0; i < 4; ++i) {
#pragma unroll
      for (int t = 0; t < 4; ++t) {
        const int colL = 64 * wv + 16 * t + lm;
        const float cs = csq[colL];
#pragma unroll
        for (int r = 0; r < 4; ++r) {
          const int rowL = 16 * i + 4 * lg + r;
          float d2 = xsq[rowL] + cs - 2.0f * acc1[i][t][r];
          d2 = fmaxf(d2, 0.f);
          const float ph = __expf(-gma * __fsqrt_rn(d2));
          phi_lds[rowL * PHI_PITCH1 + colL] = bf16t(ph);
        }
      }
    }

    for (int u = 0; u < 4; ++u) {
      __syncthreads();
      {
        const int row = tid >> 1;
        const int half = tid & 1;
        short* wr = bw_lds + row * BW_PITCH1 + half * 32;
        if (row < NK) {
          const float* ws = W + (size_t)row * NC + c0 + u * 64 + half * 32;
#pragma unroll
          for (int i = 0; i < 8; ++i) {
            f4 v = ((const f4*)ws)[i];
            short4v h;
            h.x = bf16t(v.x); h.y = bf16t(v.y); h.z = bf16t(v.z); h.w = bf16t(v.w);
            *(short4v*)(wr + i * 4) = h;
          }
        } else {
          const short4v zz = {0, 0, 0, 0};
#pragma unroll
          for (int i = 0; i < 8; ++i) *(short4v*)(wr + i * 4) = zz;
        }
      }
      __syncthreads();
#pragma unroll
      for (int s = 0; s < 2; ++s) {
        short8 pv[4], wv8[2];
#pragma unroll
        for (int i = 0; i < 4; ++i)
          pv[i] = *(const short8*)(p_base + 16 * i * PHI_PITCH1 + 64 * u + 32 * s);
#pragma unroll
        for (int n = 0; n < 2; ++n)
          wv8[n] = *(const short8*)(w_base + 16 * (2 * wv + n) * BW_PITCH1 + 32 * s);
#pragma unroll
        for (int i = 0; i < 4; ++i)
#pragma unroll
          for (int n = 0; n < 2; ++n)
            acc2[i][n] = __builtin_amdgcn_mfma_f32_16x16x32_bf16(
                pv[i], wv8[n], acc2[i][n], 0, 0, 0);
      }
    }
  }

#pragma unroll
  for (int i = 0; i < 4; ++i) {
#pragma unroll
    for (int n = 0; n < 2; ++n) {
      const int kout = 32 * wv + 16 * n + lm;
      if (kout < NK) {
        const float bb = bvec[kout];
#pragma unroll
        for (int r = 0; r < 4; ++r) {
          const int row = m0 + 16 * i + 4 * lg + r;
          out[(size_t)row * NK + kout] = acc2[i][n][r] + bb;
        }
      }
    }
  }
}

extern "C" void kernel_launch(void* const* d_in, const int* in_sizes, int n_in,
                              void* d_out, int out_size, void* d_ws, size_t ws_size,
                              hipStream_t stream) {
  (void)in_sizes; (void)n_in; (void)out_size;
  const float* x       = (const float*)d_in[0];
  const float* centers = (const float*)d_in[1];
  const float* gamma   = (const float*)d_in[2];
  const float* W       = (const float*)d_in[3];
  const float* b       = (const float*)d_in[4];
  float* out = (float*)d_out;

  if (ws_size >= (size_t)WS_NEED) {
    char* wsb = (char*)d_ws;
    char*  cbp  = wsb;                                  // 512KB fp8 centers
    float* csqp = (float*)(wsb + CB_BYTES);             // 1024 f32
    char*  wbp  = wsb + CB_BYTES + NC * 4;              // 256KB bf16 W
    prep_all<<<dim3(34), dim3(256), 0, stream>>>(centers, W, cbp, csqp, wbp);
    rbf_main<<<dim3(NB / 32), dim3(256), 0, stream>>>(x, cbp, csqp, wbp, b,
                                                      gamma, out);
  } else {
    rbf_fused_v1<<<dim3(NB / 64), dim3(256), 0, stream>>>(x, centers, gamma, W,
                                                          b, out);
  }
}